// Round 6
// baseline (92.347 us; speedup 1.0000x reference)
//
#include <hip/hip_runtime.h>
#include <hip/hip_bf16.h>

#define NWS 16
#define ZD 512
#define MM 100
#define NCOL 112             // padded col count (7 x 16)
#define HALF_BYTES 57344     // 112 cols * 256 k * 2 B
#define PANEL_BYTES 114688   // 112 cols * 512 k * 2 B
#define REPS 3               // DIAGNOSTIC: repeat einsum body to surface in rocprof top-5

typedef __attribute__((ext_vector_type(8))) short bf16x8;
typedef __attribute__((ext_vector_type(4))) float f32x4;

static __device__ __forceinline__ unsigned short f2bf(float x) {
    union { __hip_bfloat16 h; unsigned short u; } cv;
    cv.h = __float2bfloat16(x);
    return cv.u;
}

// ---------------- Kernel 0: basis fp32 [w][k][ij] -> bf16 swizzled panel
// Bt[w][half][col][k] with byte swizzle ((col&7)<<4) XOR'd into the k-offset.
__global__ __launch_bounds__(256) void prep_basis(const float* __restrict__ basis,
                                                  unsigned char* __restrict__ Bt) {
    const int idx = blockIdx.x * 256 + threadIdx.x;   // 16*64*112 = 114688
    const int col  = idx % NCOL;
    const int rest = idx / NCOL;
    const int g    = rest & 63;        // k-group of 8
    const int w    = rest >> 6;

    bf16x8 pk;
    #pragma unroll
    for (int e = 0; e < 8; ++e) {
        const int k = g * 8 + e;
        const float v = (col < MM) ? basis[((size_t)(w * ZD + k)) * MM + col] : 0.f;
        pk[e] = (short)f2bf(v);
    }
    const int half = g >> 5;
    const int gl   = g & 31;
    const size_t off = (size_t)w * PANEL_BYTES + (size_t)half * HALF_BYTES
                     + (size_t)col * 512 + (size_t)((gl * 16) ^ ((col & 7) << 4));
    *reinterpret_cast<bf16x8*>(Bt + off) = pk;
}

// ---------------- Kernel A: lie_alg = z @ basis via bf16 MFMA
// grid (16, 32), block 512 (8 waves, 16 rows each = 128 rows/block).
// Per half-K: z loaded in two dense 8-instruction bursts -> bf16 regs,
// B staged async into LDS; inner loop is pure LDS+MFMA.
__global__ __launch_bounds__(512, 4) void einsum_mfma(const float* __restrict__ z,
                                                      const unsigned char* __restrict__ Btg,
                                                      float* __restrict__ out) {
    __shared__ __align__(16) unsigned char Bs[HALF_BYTES];
    const int w     = blockIdx.x;
    const int chunk = blockIdx.y;
    const int tid   = threadIdx.x;
    const int wave  = tid >> 6;
    const int lane  = tid & 63;
    const int l15   = lane & 15;
    const int k8    = lane >> 4;

    const int row = chunk * 128 + wave * 16 + l15;
    const float* zp = z + (size_t)row * (NWS * ZD) + (size_t)w * ZD + k8 * 8;
    const unsigned char* bt = Btg + (size_t)w * PANEL_BYTES;

    int bbase[7];
    #pragma unroll
    for (int nf = 0; nf < 7; ++nf) bbase[nf] = (nf * 16 + l15) * 512;
    const int bswz = (l15 & 7) << 4;

    f32x4 acc[7];

    for (int rep = 0; rep < REPS; ++rep) {
        #pragma unroll
        for (int nf = 0; nf < 7; ++nf) acc[nf] = (f32x4){0.f, 0.f, 0.f, 0.f};

        #pragma unroll
        for (int half = 0; half < 2; ++half) {
            if (half | rep) __syncthreads();   // waves done reading previous Bs
            // async stage this half's B panel (linear lane*16; swizzle pre-baked)
            {
                const unsigned char* g = bt + half * HALF_BYTES + tid * 16;
                #pragma unroll
                for (int i = 0; i < 7; ++i) {
                    __builtin_amdgcn_global_load_lds(
                        (const __attribute__((address_space(1))) unsigned int*)(g + i * 8192),
                        (__attribute__((address_space(3))) unsigned int*)(&Bs[i * 8192 + tid * 16]),
                        16, 0, 0);
                }
            }

            // ---- z: two dense 8-inst sub-bursts -> 8 bf16x8 regs (static idx only)
            bf16x8 zb[8];
            {
                float4 zf[8];
                #pragma unroll
                for (int j = 0; j < 4; ++j) {          // steps half*8 + 0..3
                    const int s = half * 8 + j;
                    zf[2 * j]     = *reinterpret_cast<const float4*>(zp + s * 32);
                    zf[2 * j + 1] = *reinterpret_cast<const float4*>(zp + s * 32 + 4);
                }
                #pragma unroll
                for (int j = 0; j < 4; ++j) {
                    zb[j][0] = (short)f2bf(zf[2 * j].x);
                    zb[j][1] = (short)f2bf(zf[2 * j].y);
                    zb[j][2] = (short)f2bf(zf[2 * j].z);
                    zb[j][3] = (short)f2bf(zf[2 * j].w);
                    zb[j][4] = (short)f2bf(zf[2 * j + 1].x);
                    zb[j][5] = (short)f2bf(zf[2 * j + 1].y);
                    zb[j][6] = (short)f2bf(zf[2 * j + 1].z);
                    zb[j][7] = (short)f2bf(zf[2 * j + 1].w);
                }
                #pragma unroll
                for (int j = 0; j < 4; ++j) {          // steps half*8 + 4..7
                    const int s = half * 8 + 4 + j;
                    zf[2 * j]     = *reinterpret_cast<const float4*>(zp + s * 32);
                    zf[2 * j + 1] = *reinterpret_cast<const float4*>(zp + s * 32 + 4);
                }
                #pragma unroll
                for (int j = 0; j < 4; ++j) {
                    zb[4 + j][0] = (short)f2bf(zf[2 * j].x);
                    zb[4 + j][1] = (short)f2bf(zf[2 * j].y);
                    zb[4 + j][2] = (short)f2bf(zf[2 * j].z);
                    zb[4 + j][3] = (short)f2bf(zf[2 * j].w);
                    zb[4 + j][4] = (short)f2bf(zf[2 * j + 1].x);
                    zb[4 + j][5] = (short)f2bf(zf[2 * j + 1].y);
                    zb[4 + j][6] = (short)f2bf(zf[2 * j + 1].z);
                    zb[4 + j][7] = (short)f2bf(zf[2 * j + 1].w);
                }
            }
            __syncthreads();                   // B staged (drains vmcnt)

            // ---- pure LDS+MFMA inner loop
            #pragma unroll
            for (int step = 0; step < 8; ++step) {
                const int klb = (step * 64 + k8 * 16) ^ bswz;
                #pragma unroll
                for (int nf = 0; nf < 7; ++nf) {
                    const bf16x8 bfr = *reinterpret_cast<const bf16x8*>(Bs + bbase[nf] + klb);
                    acc[nf] = __builtin_amdgcn_mfma_f32_16x16x32_bf16(zb[step], bfr, acc[nf], 0, 0, 0);
                }
            }
        }

        // C layout: col = lane&15, row = (lane>>4)*4 + r  (verified R2/R3)
        const int rowbase = chunk * 128 + wave * 16 + k8 * 4;
        #pragma unroll
        for (int nf = 0; nf < 7; ++nf) {
            const int col = nf * 16 + l15;
            if (col < MM) {
                #pragma unroll
                for (int r = 0; r < 4; ++r)
                    out[((size_t)(rowbase + r) * NWS + w) * MM + col] = acc[nf][r];
            }
        }
    }
}

// ---------------- Kernel B: in-place expm of 10x10 matrices
#define EXP_NT 6

__global__ __launch_bounds__(320, 2) void expm_kernel(float* __restrict__ out) {
    __shared__ float As[64 * 100];
    const int t = threadIdx.x;
    const size_t base = (size_t)blockIdx.x * 6400;

    #pragma unroll
    for (int q = 0; q < 5; ++q) {
        const int idx = (q * 320 + t) * 4;
        *reinterpret_cast<float4*>(&As[idx]) =
            *reinterpret_cast<const float4*>(out + base + idx);
    }
    __syncthreads();

    const int m  = t / 5;
    const int c  = t - m * 5;
    const int j0 = 2 * c, j1 = j0 + 1;
    const float* A = &As[m * 100];

    float a[100];                          // statically indexed ONLY -> registers
    #pragma unroll
    for (int q = 0; q < 25; ++q) {
        const float4 v = *reinterpret_cast<const float4*>(A + q * 4);
        a[q * 4 + 0] = v.x; a[q * 4 + 1] = v.y;
        a[q * 4 + 2] = v.z; a[q * 4 + 3] = v.w;
    }

    float p0[10], p1[10];
    #pragma unroll
    for (int i = 0; i < 10; ++i) {
        p0[i] = A[i * 10 + j0] * (1.f / EXP_NT) + ((i == j0) ? 1.f : 0.f);
        p1[i] = A[i * 10 + j1] * (1.f / EXP_NT) + ((i == j1) ? 1.f : 0.f);
    }

    #pragma unroll
    for (int k = EXP_NT - 1; k >= 1; --k) {
        float n0[10], n1[10];
        #pragma unroll
        for (int i = 0; i < 10; ++i) { n0[i] = 0.f; n1[i] = 0.f; }
        #pragma unroll
        for (int kk = 0; kk < 10; ++kk) {
            const float q0 = p0[kk], q1 = p1[kk];
            #pragma unroll
            for (int i = 0; i < 10; ++i) {
                n0[i] = fmaf(a[i * 10 + kk], q0, n0[i]);
                n1[i] = fmaf(a[i * 10 + kk], q1, n1[i]);
            }
        }
        const float invk = 1.f / (float)k;
        #pragma unroll
        for (int i = 0; i < 10; ++i) {
            p0[i] = n0[i] * invk + ((i == j0) ? 1.f : 0.f);
            p1[i] = n1[i] * invk + ((i == j1) ? 1.f : 0.f);
        }
    }

    #pragma unroll
    for (int i = 0; i < 10; ++i)
        *reinterpret_cast<float2*>(out + base + m * 100 + i * 10 + j0) =
            make_float2(p0[i], p1[i]);
}

extern "C" void kernel_launch(void* const* d_in, const int* in_sizes, int n_in,
                              void* d_out, int out_size, void* d_ws, size_t ws_size,
                              hipStream_t stream) {
    const float* z     = (const float*)d_in[0];   // [4096,16,512]
    const float* basis = (const float*)d_in[1];   // [16,512,10,10]
    float* out = (float*)d_out;                   // [4096,16,10,10]
    unsigned char* Bt = (unsigned char*)d_ws;     // 16 * 114688 B = 1.83 MB

    prep_basis<<<(NWS * 64 * NCOL) / 256, 256, 0, stream>>>(basis, Bt);

    dim3 gridA(NWS, 32);
    einsum_mfma<<<gridA, 512, 0, stream>>>(z, Bt, out);

    expm_kernel<<<(4096 * NWS) / 64, 320, 0, stream>>>(out);
}

// Round 7
// 58.336 us; speedup vs baseline: 1.5830x; 1.5830x over previous
//
#include <hip/hip_runtime.h>
#include <hip/hip_bf16.h>

#define NWS 16
#define ZD 512
#define MM 100
#define NCOL 112             // padded col count (7 x 16)
#define QBYTES 28672         // quarter panel: 112 cols * 128 k * 2 B
#define PANEL_BYTES 114688   // 4 quarters

typedef __attribute__((ext_vector_type(8))) short bf16x8;
typedef __attribute__((ext_vector_type(4))) float f32x4;

static __device__ __forceinline__ unsigned short f2bf(float x) {
    union { __hip_bfloat16 h; unsigned short u; } cv;
    cv.h = __float2bfloat16(x);
    return cv.u;
}

// ---------------- Kernel 0: basis fp32 [w][k][ij] -> bf16 swizzled quarter panels
// Bt[w][q][col][kb] with byte swizzle ((col&7)<<4) XOR'd into the 256-B k-range.
__global__ __launch_bounds__(256) void prep_basis(const float* __restrict__ basis,
                                                  unsigned char* __restrict__ Bt) {
    const int idx = blockIdx.x * 256 + threadIdx.x;   // 16*64*112 = 114688
    const int col  = idx % NCOL;
    const int rest = idx / NCOL;
    const int g    = rest & 63;        // k-group of 8
    const int w    = rest >> 6;

    bf16x8 pk;
    #pragma unroll
    for (int e = 0; e < 8; ++e) {
        const int k = g * 8 + e;
        const float v = (col < MM) ? basis[((size_t)(w * ZD + k)) * MM + col] : 0.f;
        pk[e] = (short)f2bf(v);
    }
    const int q  = g >> 4;             // quarter (128 k each)
    const int gl = g & 15;             // 16-B chunk within quarter-col
    const size_t off = (size_t)w * PANEL_BYTES + (size_t)q * QBYTES
                     + (size_t)col * 256 + (size_t)((gl * 16) ^ ((col & 7) << 4));
    *reinterpret_cast<bf16x8*>(Bt + off) = pk;
}

// ---------------- Kernel A: lie_alg = z @ basis via bf16 MFMA
// grid (16, 32), block 512 (8 waves x 16 rows = 128 rows/block).
// K split into 4 quarters; B quarter-panels double-buffered in LDS (2x28.7KB);
// 2-phase pipeline: issue next quarter's STAGE+z before computing current.
__global__ __launch_bounds__(512, 4) void einsum_mfma(const float* __restrict__ z,
                                                      const unsigned char* __restrict__ Btg,
                                                      float* __restrict__ out) {
    __shared__ __align__(16) unsigned char Bs[2][QBYTES];
    const int w     = blockIdx.x;
    const int chunk = blockIdx.y;
    const int tid   = threadIdx.x;
    const int wave  = tid >> 6;
    const int lane  = tid & 63;
    const int l15   = lane & 15;
    const int k8    = lane >> 4;

    const int row = chunk * 128 + wave * 16 + l15;
    const float* zp = z + (size_t)row * (NWS * ZD) + (size_t)w * ZD + k8 * 8;
    const unsigned char* bt = Btg + (size_t)w * PANEL_BYTES;

    int bbase[7];
    #pragma unroll
    for (int nf = 0; nf < 7; ++nf) bbase[nf] = (nf * 16 + l15) * 256;
    const int bswz = (l15 & 7) << 4;

    float4 zf[8];                      // next-quarter z (in flight / resident)

    #define STAGE_Q(t, buf)                                                              \
        do {                                                                             \
            const unsigned char* gq = bt + (t) * QBYTES;                                 \
            _Pragma("unroll")                                                            \
            for (int r = 0; r < 3; ++r) {                                                \
                __builtin_amdgcn_global_load_lds(                                        \
                    (const __attribute__((address_space(1))) unsigned int*)(gq + (r * 512 + tid) * 16), \
                    (__attribute__((address_space(3))) unsigned int*)(&Bs[buf][(r * 512 + tid) * 16]),  \
                    16, 0, 0);                                                           \
            }                                                                            \
            if (tid < 256) {                                                             \
                __builtin_amdgcn_global_load_lds(                                        \
                    (const __attribute__((address_space(1))) unsigned int*)(gq + (1536 + tid) * 16),    \
                    (__attribute__((address_space(3))) unsigned int*)(&Bs[buf][(1536 + tid) * 16]),     \
                    16, 0, 0);                                                           \
            }                                                                            \
        } while (0)

    #define ZLOAD_Q(t)                                                                   \
        do {                                                                             \
            _Pragma("unroll")                                                            \
            for (int j = 0; j < 4; ++j) {                                                \
                zf[2 * j]     = *reinterpret_cast<const float4*>(zp + ((t) * 4 + j) * 32);      \
                zf[2 * j + 1] = *reinterpret_cast<const float4*>(zp + ((t) * 4 + j) * 32 + 4);  \
            }                                                                            \
        } while (0)

    f32x4 acc[7];
    #pragma unroll
    for (int nf = 0; nf < 7; ++nf) acc[nf] = (f32x4){0.f, 0.f, 0.f, 0.f};

    // prologue: quarter 0 in flight, then drain
    STAGE_Q(0, 0);
    ZLOAD_Q(0);
    __syncthreads();

    #pragma unroll
    for (int t = 0; t < 4; ++t) {
        // convert resident z (drained by previous barrier)
        bf16x8 zb[4];
        #pragma unroll
        for (int j = 0; j < 4; ++j) {
            zb[j][0] = (short)f2bf(zf[2 * j].x);
            zb[j][1] = (short)f2bf(zf[2 * j].y);
            zb[j][2] = (short)f2bf(zf[2 * j].z);
            zb[j][3] = (short)f2bf(zf[2 * j].w);
            zb[j][4] = (short)f2bf(zf[2 * j + 1].x);
            zb[j][5] = (short)f2bf(zf[2 * j + 1].y);
            zb[j][6] = (short)f2bf(zf[2 * j + 1].z);
            zb[j][7] = (short)f2bf(zf[2 * j + 1].w);
        }
        // issue next quarter's staging + z loads (hidden under compute below)
        if (t < 3) {
            STAGE_Q(t + 1, (t + 1) & 1);
            ZLOAD_Q(t + 1);
        }
        // compute current quarter: pure LDS + MFMA
        #pragma unroll
        for (int s = 0; s < 4; ++s) {
            const int klb = (s * 64 + k8 * 16) ^ bswz;
            #pragma unroll
            for (int nf = 0; nf < 7; ++nf) {
                const bf16x8 bfr = *reinterpret_cast<const bf16x8*>(&Bs[t & 1][bbase[nf] + klb]);
                acc[nf] = __builtin_amdgcn_mfma_f32_16x16x32_bf16(zb[s], bfr, acc[nf], 0, 0, 0);
            }
        }
        if (t < 3) __syncthreads();    // drains next-quarter STAGE+z; protects buffer flip
    }

    // C layout: col = lane&15, row = (lane>>4)*4 + r  (verified R2/R3)
    const int rowbase = chunk * 128 + wave * 16 + k8 * 4;
    #pragma unroll
    for (int nf = 0; nf < 7; ++nf) {
        const int col = nf * 16 + l15;
        if (col < MM) {
            #pragma unroll
            for (int r = 0; r < 4; ++r)
                out[((size_t)(rowbase + r) * NWS + w) * MM + col] = acc[nf][r];
        }
    }
    #undef STAGE_Q
    #undef ZLOAD_Q
}

// ---------------- Kernel B: in-place expm of 10x10 matrices
#define EXP_NT 6

__global__ __launch_bounds__(320, 2) void expm_kernel(float* __restrict__ out) {
    __shared__ float As[64 * 100];
    const int t = threadIdx.x;
    const size_t base = (size_t)blockIdx.x * 6400;

    #pragma unroll
    for (int q = 0; q < 5; ++q) {
        const int idx = (q * 320 + t) * 4;
        *reinterpret_cast<float4*>(&As[idx]) =
            *reinterpret_cast<const float4*>(out + base + idx);
    }
    __syncthreads();

    const int m  = t / 5;
    const int c  = t - m * 5;
    const int j0 = 2 * c, j1 = j0 + 1;
    const float* A = &As[m * 100];

    float a[100];                          // statically indexed ONLY -> registers
    #pragma unroll
    for (int q = 0; q < 25; ++q) {
        const float4 v = *reinterpret_cast<const float4*>(A + q * 4);
        a[q * 4 + 0] = v.x; a[q * 4 + 1] = v.y;
        a[q * 4 + 2] = v.z; a[q * 4 + 3] = v.w;
    }

    float p0[10], p1[10];
    #pragma unroll
    for (int i = 0; i < 10; ++i) {
        p0[i] = A[i * 10 + j0] * (1.f / EXP_NT) + ((i == j0) ? 1.f : 0.f);
        p1[i] = A[i * 10 + j1] * (1.f / EXP_NT) + ((i == j1) ? 1.f : 0.f);
    }

    #pragma unroll
    for (int k = EXP_NT - 1; k >= 1; --k) {
        float n0[10], n1[10];
        #pragma unroll
        for (int i = 0; i < 10; ++i) { n0[i] = 0.f; n1[i] = 0.f; }
        #pragma unroll
        for (int kk = 0; kk < 10; ++kk) {
            const float q0 = p0[kk], q1 = p1[kk];
            #pragma unroll
            for (int i = 0; i < 10; ++i) {
                n0[i] = fmaf(a[i * 10 + kk], q0, n0[i]);
                n1[i] = fmaf(a[i * 10 + kk], q1, n1[i]);
            }
        }
        const float invk = 1.f / (float)k;
        #pragma unroll
        for (int i = 0; i < 10; ++i) {
            p0[i] = n0[i] * invk + ((i == j0) ? 1.f : 0.f);
            p1[i] = n1[i] * invk + ((i == j1) ? 1.f : 0.f);
        }
    }

    #pragma unroll
    for (int i = 0; i < 10; ++i)
        *reinterpret_cast<float2*>(out + base + m * 100 + i * 10 + j0) =
            make_float2(p0[i], p1[i]);
}

extern "C" void kernel_launch(void* const* d_in, const int* in_sizes, int n_in,
                              void* d_out, int out_size, void* d_ws, size_t ws_size,
                              hipStream_t stream) {
    const float* z     = (const float*)d_in[0];   // [4096,16,512]
    const float* basis = (const float*)d_in[1];   // [16,512,10,10]
    float* out = (float*)d_out;                   // [4096,16,10,10]
    unsigned char* Bt = (unsigned char*)d_ws;     // 16 * 114688 B = 1.83 MB

    prep_basis<<<(NWS * 64 * NCOL) / 256, 256, 0, stream>>>(basis, Bt);

    dim3 gridA(NWS, 32);
    einsum_mfma<<<gridA, 512, 0, stream>>>(z, Bt, out);

    expm_kernel<<<(4096 * NWS) / 64, 320, 0, stream>>>(out);
}